// Round 7
// baseline (655.800 us; speedup 1.0000x reference)
//
#include <hip/hip_runtime.h>
#include <hip/hip_bf16.h>
#include <cstdint>
#include <cstddef>

typedef __bf16 bf16;
typedef unsigned char u8;
typedef unsigned short u16;
typedef __bf16 v8bf  __attribute__((ext_vector_type(8)));
typedef float  f32x4 __attribute__((ext_vector_type(4)));
typedef float  f32x16 __attribute__((ext_vector_type(16)));
typedef int    i32x4 __attribute__((ext_vector_type(4)));
typedef int    i32x2 __attribute__((ext_vector_type(2)));
typedef int    v8i32 __attribute__((ext_vector_type(8)));

// ---------------------------------------------------------------- async copy
__device__ __forceinline__ void async16(void* lds, const void* g) {
  __builtin_amdgcn_global_load_lds(
      (const __attribute__((address_space(1))) unsigned int*)g,
      (__attribute__((address_space(3))) unsigned int*)lds, 16, 0, 0);
}

// LDS tiles XOR-swizzled at 16B quarter granularity.
// Big GEMM: MX fp8 e4m3, K padded 18592->18624 = 291 windows of 64.
// B pre-scaled by 2^5 at pack; HW block scale 0x7A (=2^-5) undoes it.
// R7: LDS-port model CONFIRMED by R6 (conflicts scaled exactly 0.75x with
// reads; time tracks read traffic; MfmaUtil*dur == 33us MFMA floor every
// round). Crank the same lever: block 256x256, wave tile 128x128 ->
// 16 ds_read_b128 per 16 MFMAs (1.0 vs 1.5). Port/CU/window: 4x16x16 +
// 256 DMA = 1280 cyc for 64 MFMAs -> ~39us port vs 33us MFMA floor.
// acc[4][4] f32x16 = 256 regs -> AGPRs (unified RF). 1 block/CU.

// ================================================================ prologue device funcs
__device__ __forceinline__ void pairs_dev(u16* __restrict__ pairs, float* __restrict__ stats) {
  int r = threadIdx.x;
  if (r < 128) stats[r] = 0.f;   // zero BN accumulators (sum, sumsq)
  if (r < 192) {
    int off = 192 * r - (r * (r - 1)) / 2;
    for (int c = r; c < 192; ++c) pairs[off + c - r] = (u16)((r << 8) | c);
  } else if (r == 192) {
    for (int j = 0; j < 64; ++j) pairs[18528 + j] = (u16)((j << 8) | 192);
  } else if (r == 193) {
    for (int j = 18592; j < 18624; ++j) pairs[j] = (u16)((192 << 8) | 192);  // pad (B=0)
  }
}

// pack A (f32 row-major -> bf16 tiles [mt][kt][64][32])
__device__ __forceinline__ void packA_dev(const float* __restrict__ A,
                                          bf16* __restrict__ Ap, int K,
                                          int bx, int by) {
  const int t = threadIdx.x;
  const int KT = K >> 5;
  const size_t tile = ((size_t)bx * KT + by) * (64 * 32);
  const int c = t;
  const int mm = c >> 2, koct = (c & 3) * 8;
  const float* src = A + (size_t)(bx * 64 + mm) * K + by * 32 + koct;
  f32x4 f0 = *(const f32x4*)src;
  f32x4 f1 = *(const f32x4*)(src + 4);
  __align__(16) bf16 h[8];
  h[0]=(bf16)f0[0]; h[1]=(bf16)f0[1]; h[2]=(bf16)f0[2]; h[3]=(bf16)f0[3];
  h[4]=(bf16)f1[0]; h[5]=(bf16)f1[1]; h[6]=(bf16)f1[2]; h[7]=(bf16)f1[3];
  *(i32x4*)(Ap + tile + (size_t)c * 8) = *(const i32x4*)h;
}

// pack B (f32 [K][N] -> bf16 tiles [nt][kt][64][32])
__device__ __forceinline__ void packB_dev(const float* __restrict__ B,
                                          bf16* __restrict__ Bp, int K, int N,
                                          int bx, int by,
                                          float* __restrict__ sLB) {
  const int BNp = 64, LS = 66;
  const int t = threadIdx.x;
  const int KT = K >> 5;
  for (int idx = t; idx < 32 * BNp; idx += 256) {
    const int kk = idx >> 6, nn = idx & 63;
    sLB[kk * LS + nn] = B[(size_t)(by * 32 + kk) * N + bx * BNp + nn];
  }
  __syncthreads();
  const size_t tile = ((size_t)bx * KT + by) * ((size_t)BNp * 32);
  for (int c = t; c < BNp * 4; c += 256) {
    const int nn = c >> 2, koct = (c & 3) * 8;
    __align__(16) bf16 h[8];
#pragma unroll
    for (int j = 0; j < 8; ++j) h[j] = (bf16)sLB[(koct + j) * LS + nn];
    *(i32x4*)(Bp + tile + (size_t)c * 8) = *(const i32x4*)h;
  }
}

// pack tw1 -> fp8 e4m3 tiles [nt 8][kw 291][n 128][k 64 B], values *32.
__device__ __forceinline__ void packTw1_dev(const float* __restrict__ tw1,
                                            u8* __restrict__ Bp, int nt, int kw) {
  const int t = threadIdx.x;
  const int n4 = t & 31, k8 = t >> 5;
  const int kbase = kw * 64 + k8 * 8;
  const int nbase = nt * 128 + n4 * 4;
  f32x4 v[8];
#pragma unroll
  for (int j = 0; j < 8; ++j) {
    const int gk = kbase + j;
    if (gk < 18592) {
      v[j] = *(const f32x4*)(tw1 + (size_t)gk * 1024 + nbase);
      v[j] *= 32.f;
    } else {
      v[j] = f32x4{0.f, 0.f, 0.f, 0.f};
    }
  }
  u8* tile = Bp + ((size_t)nt * 291 + kw) * 8192;
#pragma unroll
  for (int c = 0; c < 4; ++c) {
    int r0 = __builtin_amdgcn_cvt_pk_fp8_f32(v[0][c], v[1][c], 0, false);
    r0 = __builtin_amdgcn_cvt_pk_fp8_f32(v[2][c], v[3][c], r0, true);
    int r1 = __builtin_amdgcn_cvt_pk_fp8_f32(v[4][c], v[5][c], 0, false);
    r1 = __builtin_amdgcn_cvt_pk_fp8_f32(v[6][c], v[7][c], r1, true);
    i32x2 d; d[0] = r0; d[1] = r1;
    *(i32x2*)(tile + (n4 * 4 + c) * 64 + k8 * 8) = d;
  }
}

// ---------------------------------------------------------------- fused prologue
__global__ __launch_bounds__(256) void prologue_kernel(
    const float* __restrict__ xep, const float* __restrict__ xd,
    const float* __restrict__ pw1, const float* __restrict__ pw2,
    const float* __restrict__ bw1, const float* __restrict__ bw2,
    const float* __restrict__ tw1, const float* __restrict__ tw2,
    bf16* Xp, bf16* Xd, bf16* Bpw1, bf16* Bpw2, bf16* Bbw1, bf16* Bbw2,
    u8* Btw1, bf16* Btw2, u16* pairs, float* stats) {
  __shared__ float sLB[32 * 66];
  int i = blockIdx.x;
  if (i < 2328) { packTw1_dev(tw1, Btw1, i & 7, i >> 3); return; }
  i -= 2328;
  if (i < 1536) { packA_dev(xep, Xp, 768, i & 63, i >> 6); return; }
  i -= 1536;
  if (i < 512)  { packA_dev(xd, Xd, 256, i & 63, i >> 6); return; }
  i -= 512;
  if (i < 96)   { packB_dev(pw1, Bpw1, 768, 256, i & 3, i >> 2, sLB); return; }
  i -= 96;
  if (i < 8)    { packB_dev(pw2, Bpw2, 256, 64, 0, i, sLB); return; }
  i -= 8;
  if (i < 64)   { packB_dev(bw1, Bbw1, 256, 512, i & 7, i >> 3, sLB); return; }
  i -= 64;
  if (i < 16)   { packB_dev(bw2, Bbw2, 512, 64, 0, i, sLB); return; }
  i -= 16;
  if (i < 256)  { packB_dev(tw2, Btw2, 1024, 512, i & 7, i >> 3, sLB); return; }
  i -= 256;
  if (i == 0) pairs_dev(pairs, stats);
}

// embedding gather-sum -> cf[:,128:192], 8 rows per block
__device__ __forceinline__ void embed8_dev(const int* __restrict__ xs,
                                           const float* __restrict__ emb,
                                           float* __restrict__ cf, int blk) {
  const int wid = threadIdx.x >> 6, lane = threadIdx.x & 63;
#pragma unroll
  for (int s = 0; s < 2; ++s) {
    const int b = blk * 8 + s * 4 + wid;
    const int* row = xs + (size_t)b * 50;
    float acc = 0.f;
#pragma unroll 10
    for (int h = 0; h < 50; ++h) {
      int idx = row[h];
      acc += emb[(size_t)idx * 64 + lane];
    }
    cf[(size_t)b * 193 + 128 + lane] = acc;
  }
}

// ================================================================ bf16 MFMA GEMM body (small GEMMs)
template <int BM, int BN, int MF, int NF>
__device__ __forceinline__ void gemm_body(
    const bf16* __restrict__ Ap, const bf16* __restrict__ Bp,
    const float* __restrict__ bias,
    float* __restrict__ outF, int ldF,
    bf16* __restrict__ outP, int ktN, int bmsh,
    int KT, int M0, int relu_flag, int bx, int by,
    bf16* sA, bf16* sB, float* statsAcc) {
  const int t = threadIdx.x;
  const int wid = t >> 6, lane = t & 63;
  const int wm = (wid >> 1) * (MF * 16);
  const int wn = (wid & 1) * (NF * 16);
  const int r16 = lane & 15, q = lane >> 4;

  f32x4 acc[MF][NF];
#pragma unroll
  for (int i = 0; i < MF; ++i)
#pragma unroll
    for (int j = 0; j < NF; ++j) acc[i][j] = f32x4{0.f, 0.f, 0.f, 0.f};

  const bf16* aBase = Ap + (size_t)bx * KT * (BM * 32);
  const bf16* bBase = Bp + (size_t)by * KT * (BN * 32);
  constexpr int A_CH = BM * 4;
  constexpr int B_CH = BN * 4;

  for (int kt = 0; kt < KT; ++kt) {
    const bf16* ag = aBase + (size_t)kt * (BM * 32);
    const bf16* bg = bBase + (size_t)kt * (BN * 32);
#pragma unroll
    for (int c = t; c < A_CH; c += 256) {
      const int row = c >> 2, qs = c & 3, qg = (qs - (row >> 1)) & 3;
      async16(sA + c * 8, ag + row * 32 + qg * 8);
    }
#pragma unroll
    for (int c = t; c < B_CH; c += 256) {
      const int row = c >> 2, qs = c & 3, qg = (qs - (row >> 1)) & 3;
      async16(sB + c * 8, bg + row * 32 + qg * 8);
    }
    __syncthreads();
    v8bf af[MF], bfr[NF];
#pragma unroll
    for (int i = 0; i < MF; ++i) {
      const int row = wm + i * 16 + r16;
      af[i] = *(const v8bf*)(sA + row * 32 + (((q + (row >> 1)) & 3) * 8));
    }
#pragma unroll
    for (int j = 0; j < NF; ++j) {
      const int row = wn + j * 16 + r16;
      bfr[j] = *(const v8bf*)(sB + row * 32 + (((q + (row >> 1)) & 3) * 8));
    }
#pragma unroll
    for (int i = 0; i < MF; ++i)
#pragma unroll
      for (int j = 0; j < NF; ++j)
        acc[i][j] = __builtin_amdgcn_mfma_f32_16x16x32_bf16(af[i], bfr[j], acc[i][j], 0, 0, 0);
    __syncthreads();
  }

  float cs[NF], cs2[NF];
#pragma unroll
  for (int j = 0; j < NF; ++j) { cs[j] = 0.f; cs2[j] = 0.f; }

#pragma unroll
  for (int j = 0; j < NF; ++j) {
    const int gn = by * BN + wn + j * 16 + r16;
    const float bv = bias[gn];
#pragma unroll
    for (int i = 0; i < MF; ++i) {
      const int gm0 = M0 + bx * BM + wm + i * 16 + q * 4;
#pragma unroll
      for (int r = 0; r < 4; ++r) {
        float v = acc[i][j][r] + bv;
        if (relu_flag) v = fmaxf(v, 0.f);
        if (statsAcc) { cs[j] += v; cs2[j] += v * v; }
        const int gm = gm0 + r;
        if (outF) outF[(size_t)gm * ldF + gn] = v;
        if (outP) {
          const int mt = gm >> bmsh, mm = gm & ((1 << bmsh) - 1);
          outP[(((size_t)mt * ktN + (gn >> 5)) << (bmsh + 5)) + ((size_t)mm << 5) + (gn & 31)] = (bf16)v;
        }
      }
    }
  }

  if (statsAcc) {
#pragma unroll
    for (int j = 0; j < NF; ++j) {
      float a = cs[j], b2 = cs2[j];
      a += __shfl_xor(a, 16, 64);  a += __shfl_xor(a, 32, 64);
      b2 += __shfl_xor(b2, 16, 64); b2 += __shfl_xor(b2, 32, 64);
      if (q == 0) {
        const int gn = by * BN + wn + j * 16 + r16;
        atomicAdd(&statsAcc[gn], a);
        atomicAdd(&statsAcc[64 + gn], b2);
      }
    }
  }
}

template <int BM, int BN, int MF, int NF>
__global__ __launch_bounds__(256, 2) void gemm_kernel(
    const bf16* __restrict__ Ap, const bf16* __restrict__ Bp,
    const float* __restrict__ bias,
    float* __restrict__ outF, int ldF,
    bf16* __restrict__ outP, int ktN, int bmsh,
    int KT, int M0, int relu_flag) {
  __shared__ __align__(16) bf16 sA[BM * 32];
  __shared__ __align__(16) bf16 sB[BN * 32];
  gemm_body<BM, BN, MF, NF>(Ap, Bp, bias, outF, ldF, outP, ktN, bmsh,
                            KT, M0, relu_flag, blockIdx.x, blockIdx.y, sA, sB, nullptr);
}

// two independent GEMMs (z=0,1) + optional embed slice (z=2)
template <int BM, int BN, int MF, int NF>
__global__ __launch_bounds__(256, 2) void gemm_dual_kernel(
    const bf16* Ap0, const bf16* Bp0, const float* bias0,
    float* outF0, int ldF0, bf16* outP0, int ktN0, int bmsh0, int KT0, int relu0, int gy0,
    float* statsAcc0,
    const bf16* Ap1, const bf16* Bp1, const float* bias1,
    float* outF1, int ldF1, bf16* outP1, int ktN1, int bmsh1, int KT1, int relu1, int gy1,
    const int* xs, const float* emb, float* cf) {
  __shared__ __align__(16) bf16 sA[BM * 32];
  __shared__ __align__(16) bf16 sB[BN * 32];
  if (blockIdx.z == 0) {
    if ((int)blockIdx.y >= gy0) return;
    gemm_body<BM, BN, MF, NF>(Ap0, Bp0, bias0, outF0, ldF0, outP0, ktN0, bmsh0,
                              KT0, 0, relu0, blockIdx.x, blockIdx.y, sA, sB, statsAcc0);
  } else if (blockIdx.z == 1) {
    if ((int)blockIdx.y >= gy1) return;
    gemm_body<BM, BN, MF, NF>(Ap1, Bp1, bias1, outF1, ldF1, outP1, ktN1, bmsh1,
                              KT1, 0, relu1, blockIdx.x, blockIdx.y, sA, sB, nullptr);
  } else {
    embed8_dev(xs, emb, cf, blockIdx.y * 64 + blockIdx.x);
  }
}

// ---------------------------------------------------------------- MX fp8 split-K GEMM -> bf16 partials [S][Mchunk][1024]
// Block tile 256x256 (2 A mt-tiles x 2 B nt-tiles), 4 waves of 128x128.
// Per window: A 16KB + B 16KB = 32KB/slot, 2 slots = 64KB LDS.
// Per thread per window: 16 ds_read_b128 feed 16 MFMAs (1.0 vs 1.5 at
// 256x128) — port/CU/window 1280 cyc for 64 MFMAs. acc[4][4] f32x16 in
// AGPRs. Counted-vmcnt window pipeline (R5/R6-proven): stage w+1 (8 DMAs),
// vmcnt(8) retires window w's 8, barrier, compute, lgkmcnt(0), barrier.
template <int S>
__global__ __launch_bounds__(256, 1) void gemm_splitk_mx(
    const u8* __restrict__ Ap, const u8* __restrict__ Bp,
    bf16* __restrict__ part, int Mchunk) {
  __shared__ __align__(16) u8 sAB[65536];   // 2 slots x (A 16KB + B 16KB)
  const int t = threadIdx.x;
  const int bx = blockIdx.x, by = blockIdx.y, bz = blockIdx.z;
  const int lane = t & 63, wid = t >> 6;
  const int wm2 = (wid >> 1) * 128, wn2 = (wid & 1) * 128;  // wave tile 128x128
  const int l31 = lane & 31, khalf = lane >> 5;
  const int kw0 = (291 * bz) / S, kw1 = (291 * (bz + 1)) / S;
  const int nw = kw1 - kw0;

  // ---- staging offsets (pre-swizzled source; LDS dst lane-linear) ----
  // chunk c in [0,1024): row = c>>2 (0..255), qs = c&3,
  // source quarter qg = (qs - (row>>1)) & 3; rows >=128 live in tile+1.
  const size_t TILE1 = (size_t)291 * 8192;
  size_t aSrc[4]; int aDst[4];
  size_t bSrc[4]; int bDst[4];
#pragma unroll
  for (int k = 0; k < 4; ++k) {
    const int c = t + 256 * k;
    const int rw = c >> 2;
    const int qg = ((c & 3) - (rw >> 1)) & 3;
    const size_t src = (rw >= 128 ? TILE1 + (size_t)(rw - 128) * 64
                                  : (size_t)rw * 64) + qg * 16;
    aSrc[k] = src;          aDst[k] = t * 16 + k * 4096;
    bSrc[k] = src;          bDst[k] = 16384 + t * 16 + k * 4096;
  }

  // ---- read fragment LDS offsets (swizzled quarters) ----
  int fa0[4], fa1[4], fb0[4], fb1[4];
#pragma unroll
  for (int i = 0; i < 4; ++i) {
    const int ra = wm2 + i * 32 + l31;
    const int qa = (khalf * 2 + (ra >> 1)) & 3;
    fa0[i] = ra * 64 + qa * 16;
    fa1[i] = ra * 64 + (((qa + 1) & 3) << 4);
    const int rb = wn2 + i * 32 + l31;
    const int qb = (khalf * 2 + (rb >> 1)) & 3;
    fb0[i] = 16384 + rb * 64 + qb * 16;
    fb1[i] = 16384 + rb * 64 + (((qb + 1) & 3) << 4);
  }

  f32x16 acc[4][4];
#pragma unroll
  for (int i = 0; i < 4; ++i)
#pragma unroll
    for (int j = 0; j < 4; ++j)
#pragma unroll
      for (int r = 0; r < 16; ++r) acc[i][j][r] = 0.f;

  const u8* agp = Ap + ((size_t)(bx * 2) * 291 + kw0) * 8192;
  const u8* bgp = Bp + ((size_t)(by * 2) * 291 + kw0) * 8192;

  auto stageW = [&](int w) {                 // exactly 8 DMAs per call
    const int slot = (w & 1) * 32768;
    const u8* ag = agp + (size_t)w * 8192;
    const u8* bg = bgp + (size_t)w * 8192;
#pragma unroll
    for (int k = 0; k < 4; ++k) async16(&sAB[slot + aDst[k]], ag + aSrc[k]);
#pragma unroll
    for (int k = 0; k < 4; ++k) async16(&sAB[slot + bDst[k]], bg + bSrc[k]);
  };

  auto compute = [&](int off) {
    v8i32 bv[4];
#pragma unroll
    for (int j = 0; j < 4; ++j) {
      union { i32x4 h[2]; v8i32 v; } ub;
      ub.h[0] = *(const i32x4*)&sAB[fb0[j] + off];
      ub.h[1] = *(const i32x4*)&sAB[fb1[j] + off];
      bv[j] = ub.v;
    }
#pragma unroll
    for (int i = 0; i < 4; ++i) {
      union { i32x4 h[2]; v8i32 v; } ua;
      ua.h[0] = *(const i32x4*)&sAB[fa0[i] + off];
      ua.h[1] = *(const i32x4*)&sAB[fa1[i] + off];
#pragma unroll
      for (int j = 0; j < 4; ++j)
        acc[i][j] = __builtin_amdgcn_mfma_scale_f32_32x32x64_f8f6f4(
            ua.v, bv[j], acc[i][j], 0, 0, 0, 0x7F7F7F7F, 0, 0x7A7A7A7A);
    }
  };

  stageW(0);                                  // 8 outstanding
  for (int w = 0; w < nw; ++w) {
    if (w + 1 < nw) {
      stageW(w + 1);                          // +8 -> 16 outstanding
      asm volatile("s_waitcnt vmcnt(8)" ::: "memory");   // retire window w's 8
    } else {
      asm volatile("s_waitcnt vmcnt(0)" ::: "memory");   // final window: drain
    }
    __builtin_amdgcn_s_barrier();             // window w resident for all waves
    __builtin_amdgcn_sched_barrier(0);        // no ds_read hoists above barrier
    compute((w & 1) * 32768);
    if (w + 1 < nw) {
      asm volatile("s_waitcnt lgkmcnt(0)" ::: "memory"); // ds_reads drained
      __builtin_amdgcn_s_barrier();           // slot free for stageW(w+2)
    }
  }

  bf16* pBase = part + (size_t)bz * Mchunk * 1024;
#pragma unroll
  for (int i = 0; i < 4; ++i)
#pragma unroll
    for (int j = 0; j < 4; ++j) {
      const int gn = by * 256 + wn2 + j * 32 + l31;
#pragma unroll
      for (int r = 0; r < 16; ++r) {
        const int gm = bx * 256 + wm2 + i * 32 + (r & 3) + 8 * (r >> 2) + 4 * khalf;
        pBase[(size_t)gm * 1024 + gn] = (bf16)acc[i][j][r];
      }
    }
}

// ---------------------------------------------------------------- split-K reduce -> t1 packed bf16 (BM=64)
__global__ __launch_bounds__(256) void reducek_kernel(const bf16* __restrict__ part,
                                                      const float* __restrict__ bias,
                                                      bf16* __restrict__ t1,
                                                      int S, int Mchunk, int M0) {
  const int idx = blockIdx.x * 256 + threadIdx.x;
  const int gm = idx >> 7;
  const int gn8 = (idx & 127) * 8;
  float v[8] = {0.f, 0.f, 0.f, 0.f, 0.f, 0.f, 0.f, 0.f};
  for (int s = 0; s < S; ++s) {
    v8bf p = *(const v8bf*)(part + ((size_t)s * Mchunk + gm) * 1024 + gn8);
#pragma unroll
    for (int r = 0; r < 8; ++r) v[r] += (float)p[r];
  }
  const f32x4 b0 = *(const f32x4*)(bias + gn8);
  const f32x4 b1 = *(const f32x4*)(bias + gn8 + 4);
  __align__(16) bf16 h[8];
#pragma unroll
  for (int r = 0; r < 4; ++r) h[r] = (bf16)fmaxf(v[r] + b0[r], 0.f);
#pragma unroll
  for (int r = 0; r < 4; ++r) h[4 + r] = (bf16)fmaxf(v[4 + r] + b1[r], 0.f);
  const int G = M0 + gm;
  const int mt = G >> 6, mm = G & 63, kt = gn8 >> 5;
  *(i32x4*)(t1 + (((size_t)mt * 32 + kt) << 11) + (mm << 5) + (gn8 & 31)) = *(const i32x4*)h;
}

// ---------------------------------------------------------------- interaction A -> fp8 tiles [mt][kw 291][128][64]
__global__ __launch_bounds__(256, 2) void agen_kernel(const float* __restrict__ cf,
                                                      const float* __restrict__ z,
                                                      const float* __restrict__ gsum,
                                                      const float* __restrict__ gamma,
                                                      const float* __restrict__ beta,
                                                      const u16* __restrict__ pairs,
                                                      u8* __restrict__ Ap,
                                                      float* __restrict__ dout,
                                                      int rowBase) {
  __shared__ float sCF[64 * 193];
  __shared__ float sMu[64], sRstd[64];
  const int t = threadIdx.x;
  const int gRow0 = rowBase + blockIdx.x * 64;
  // bottom cols 0:64
  for (int idx = t; idx < 64 * 64; idx += 256) {
    const int r = idx >> 6, c = idx & 63;
    sCF[r * 193 + c] = cf[(size_t)(gRow0 + r) * 193 + c];
  }
  // embed cols 128:192
  for (int idx = t; idx < 64 * 64; idx += 256) {
    const int r = idx >> 6, c = idx & 63;
    sCF[r * 193 + 128 + c] = cf[(size_t)(gRow0 + r) * 193 + 128 + c];
  }
  if (t < 64) {
    const float mu = gsum[t] * (1.f / 4096.f);
    const float var = gsum[64 + t] * (1.f / 4096.f) - mu * mu;
    sMu[t] = mu;
    sRstd[t] = rsqrtf(var + 1e-5f);
    sCF[t * 193 + 192] = 1.f;
  }
  __syncthreads();
  // normalize z -> cols 64:128 (+ dout tail once)
  for (int idx = t; idx < 64 * 64; idx += 256) {
    const int r = idx >> 6, c = idx & 63;
    const float xe = gamma[c] * (z[(size_t)(gRow0 + r) * 64 + c] - sMu[c]) * sRstd[c] + beta[c];
    sCF[r * 193 + 64 + c] = xe;
    if (blockIdx.y == 0) dout[4096 + (size_t)(gRow0 + r) * 64 + c] = xe;
  }
  __syncthreads();

  const int kw0 = (291 * blockIdx.y) / 8;
  const int kw1 = (291 * (blockIdx.y + 1)) / 8;
  const int row = t >> 2, kq = t & 3;
  const int mt = blockIdx.x >> 1;
  const int mrow = (blockIdx.x & 1) * 64 + row;
  const float* myrow = sCF + row * 193;
  for (int kw = kw0; kw < kw1; ++kw) {
    const int kb = kw * 64 + kq * 16;
    i32x4 d;
    if (kb >= 18592) {
      d = i32x4{0, 0, 0, 0};
    } else {
      union { i32x4 v4[2]; u16 u[16]; } P;
      P.v4[0] = *(const i32x4*)(pairs + kb);
      P.v4[1] = *(const i32x4*)(pairs + kb + 8);
#pragma unroll
      for (int g = 0; g < 4; ++g) {
        float p[4];
#pragma unroll
        for (int j = 0; j < 4; ++j) {
          const u16 pr = P.u[g * 4 + j];
          p[j] = myrow[pr >> 8] * myrow[pr & 255];
        }
        int r = __builtin_amdgcn_cvt_pk_fp8_f32(p[0], p[1], 0, false);
        r = __builtin_amdgcn_cvt_pk_fp8_f32(p[2], p[3], r, true);
        d[g] = r;
      }
    }
    *(i32x4*)(Ap + (((size_t)mt * 291 + kw) * 128 + mrow) * 64 + kq * 16) = d;
  }
}

// ---------------------------------------------------------------- final dot (512->1) + sigmoid; t2 packed bf16 (BM=64, N=512)
__global__ __launch_bounds__(256) void topdot_kernel(const bf16* __restrict__ t2p,
                                                     const float* __restrict__ w,
                                                     const float* __restrict__ b3,
                                                     float* __restrict__ dout) {
  const int wid = threadIdx.x >> 6, lane = threadIdx.x & 63;
  const int b = blockIdx.x * 4 + wid;
  // lane covers n = lane*8 .. lane*8+7
  const size_t addr = ((((size_t)(b >> 6) * 16) + (lane >> 2)) << 11) +
                      ((size_t)(b & 63) << 5) + (lane & 3) * 8;
  v8bf p = *(const v8bf*)(t2p + addr);
  const float* wv = w + lane * 8;
  float s = 0.f;
#pragma unroll
  for (int r = 0; r < 8; ++r) s += (float)p[r] * wv[r];
  for (int m = 32; m > 0; m >>= 1) s += __shfl_xor(s, m, 64);
  if (lane == 0) dout[b] = 1.f / (1.f + __expf(-(s + b3[0])));
}

// ================================================================ launch
extern "C" void kernel_launch(void* const* d_in, const int* in_sizes, int n_in,
                              void* d_out, int out_size, void* d_ws, size_t ws_size,
                              hipStream_t stream) {
  const int*   xs   = (const int*)  d_in[0];
  const float* xd   = (const float*)d_in[1];
  const float* xep  = (const float*)d_in[2];
  const float* emb  = (const float*)d_in[3];
  const float* pw1  = (const float*)d_in[4];
  const float* pb1  = (const float*)d_in[5];
  const float* pw2  = (const float*)d_in[6];
  const float* pb2  = (const float*)d_in[7];
  const float* gmma = (const float*)d_in[8];
  const float* beta = (const float*)d_in[9];
  const float* bw1  = (const float*)d_in[10];
  const float* bb1  = (const float*)d_in[11];
  const float* bw2  = (const float*)d_in[12];
  const float* bb2  = (const float*)d_in[13];
  const float* tw1  = (const float*)d_in[14];
  const float* tb1  = (const float*)d_in[15];
  const float* tw2  = (const float*)d_in[16];
  const float* tb2  = (const float*)d_in[17];
  const float* tw3  = (const float*)d_in[18];
  const float* tb3  = (const float*)d_in[19];
  float* out = (float*)d_out;

  uint8_t* base = (uint8_t*)d_ws;
  size_t off = 0;
  auto alloc = [&](size_t b) {
    void* p = base + off;
    off = (off + b + 511) & ~((size_t)511);
    return p;
  };
  u16*  pairs = (u16*) alloc((size_t)18624 * 2);
  bf16* Xp    = (bf16*)alloc((size_t)4096 * 768 * 2);
  bf16* Xd    = (bf16*)alloc((size_t)4096 * 256 * 2);
  bf16* Bpw1  = (bf16*)alloc((size_t)768 * 256 * 2);
  bf16* Bpw2  = (bf16*)alloc((size_t)256 * 64 * 2);
  bf16* Bbw1  = (bf16*)alloc((size_t)256 * 512 * 2);
  bf16* Bbw2  = (bf16*)alloc((size_t)512 * 64 * 2);
  u8*   Btw1  = (u8*)  alloc((size_t)8 * 291 * 8192);
  bf16* Btw2  = (bf16*)alloc((size_t)1024 * 512 * 2);
  bf16* hbuf  = (bf16*)alloc((size_t)4096 * 256 * 2);
  float* z    = (float*)alloc((size_t)4096 * 64 * 4);
  float* stats= (float*)alloc((size_t)128 * 4);
  bf16* b0    = (bf16*)alloc((size_t)4096 * 512 * 2);
  float* cf   = (float*)alloc((size_t)4096 * 193 * 4);
  bf16* t1    = (bf16*)alloc((size_t)4096 * 1024 * 2);
  bf16* t2p   = (bf16*)alloc((size_t)4096 * 512 * 2);
  size_t fixedEnd = off;

  // pick (chunk, S): Ap fp8 = chunk*18624 B; partK bf16 = S*chunk*1024*2 B
  int chunk = 512, S = 8;
  {
    const int candC[5] = {4096, 2048, 2048, 1024, 512};
    const int candS[5] = {4, 8, 4, 8, 8};
    for (int i = 0; i < 5; ++i) {
      size_t need = fixedEnd + (size_t)candC[i] * 18624 + 1024 +
                    (size_t)candS[i] * candC[i] * 1024 * 2 + 1024;
      if (need <= ws_size) { chunk = candC[i]; S = candS[i]; break; }
    }
  }
  u8*   ApBig = (u8*)  alloc((size_t)chunk * 18624);
  bf16* partK = (bf16*)alloc((size_t)S * chunk * 1024 * 2);

  // ---- fused prologue (packs + pairs + stats zero) ----
  prologue_kernel<<<4817, 256, 0, stream>>>(
      xep, xd, pw1, pw2, bw1, bw2, tw1, tw2,
      Xp, Xd, Bpw1, Bpw2, Bbw1, Bbw2, Btw1, Btw2, pairs, stats);

  // ---- dual1: proj1 || bot1 || embed (z=2) ----
  gemm_dual_kernel<64, 64, 2, 2><<<dim3(64, 8, 3), 256, 0, stream>>>(
      Xp, Bpw1, pb1, nullptr, 0, hbuf, 8, 6, 24, 1, 4, nullptr,
      Xd, Bbw1, bb1, nullptr, 0, b0, 16, 6, 8, 1, 8,
      xs, emb, cf);
  // ---- dual2: proj2 (h@pw2 -> z f32 + BN stats atomics) || bot2 -> cf[:,0:64] ----
  gemm_dual_kernel<64, 64, 2, 2><<<dim3(64, 1, 2), 256, 0, stream>>>(
      hbuf, Bpw2, pb2, z, 64, nullptr, 0, 0, 8, 0, 1, stats,
      b0, Bbw2, bb2, cf, 193, nullptr, 0, 0, 16, 1, 1,
      nullptr, nullptr, nullptr);

  // ---- interaction (fp8, BN fused) + MX split-K GEMM + reduce ----
  for (int c0 = 0; c0 < 4096; c0 += chunk) {
    agen_kernel<<<dim3(chunk / 64, 8), 256, 0, stream>>>(
        cf, z, stats, gmma, beta, pairs, ApBig, out, c0);
    if (S == 4)
      gemm_splitk_mx<4><<<dim3(chunk / 256, 4, 4), 256, 0, stream>>>(
          ApBig, Btw1, partK, chunk);
    else
      gemm_splitk_mx<8><<<dim3(chunk / 256, 4, 8), 256, 0, stream>>>(
          ApBig, Btw1, partK, chunk);
    reducek_kernel<<<chunk / 2, 256, 0, stream>>>(partK, tb1, t1, S, chunk, c0);
  }

  // ---- top2: t2p = relu(t1@tw2+tb2) packed bf16 ----
  gemm_kernel<64, 64, 2, 2><<<dim3(64, 8), 256, 0, stream>>>(
      t1, Btw2, tb2, nullptr, 0, t2p, 16, 6, 32, 0, 1);
  // ---- top3: sigmoid(t2p@tw3+tb3) -> out[0:4096] ----
  topdot_kernel<<<1024, 256, 0, stream>>>(t2p, tw3, tb3, out);
}

// Round 9
// 331.564 us; speedup vs baseline: 1.9779x; 1.9779x over previous
//
#include <hip/hip_runtime.h>
#include <hip/hip_bf16.h>
#include <cstdint>
#include <cstddef>

typedef __bf16 bf16;
typedef unsigned char u8;
typedef unsigned short u16;
typedef __bf16 v8bf  __attribute__((ext_vector_type(8)));
typedef float  f32x4 __attribute__((ext_vector_type(4)));
typedef float  f32x16 __attribute__((ext_vector_type(16)));
typedef int    i32x4 __attribute__((ext_vector_type(4)));
typedef int    i32x2 __attribute__((ext_vector_type(2)));
typedef int    v8i32 __attribute__((ext_vector_type(8)));

// ---------------------------------------------------------------- async copy
__device__ __forceinline__ void async16(void* lds, const void* g) {
  __builtin_amdgcn_global_load_lds(
      (const __attribute__((address_space(1))) unsigned int*)g,
      (__attribute__((address_space(3))) unsigned int*)lds, 16, 0, 0);
}

// LDS tiles XOR-swizzled at 16B quarter granularity.
// Big GEMM: MX fp8 e4m3, K padded 18592->18624 = 291 windows of 64.
// B pre-scaled by 2^5 at pack; HW block scale 0x7A (=2^-5) undoes it.
// R9 = R6 (proven 66.6us splitk / 341.2us total) + s_setprio around MFMA.
// SESSION RULE (R2/R3/R8, 6/6 container kills vs 0/12 otherwise): the
// structure {per-lane global loads + global_load_lds + counted nonzero
// vmcnt} is BANNED — kills containers every time. B-in-registers lever
// unreachable; splitk is at its b128-LDS-port plateau (~16 cyc/wave-read,
// invariant 4.0 conflict-cyc/read across R0/R4/R6 = b128 intrinsic, not
// fixable by swizzle). T5 setprio predicted NULL on this 2-phase
// structure (catalog m190/m230) — free probe + baseline re-establishment.

// ================================================================ prologue device funcs
__device__ __forceinline__ void pairs_dev(u16* __restrict__ pairs, float* __restrict__ stats) {
  int r = threadIdx.x;
  if (r < 128) stats[r] = 0.f;   // zero BN accumulators (sum, sumsq)
  if (r < 192) {
    int off = 192 * r - (r * (r - 1)) / 2;
    for (int c = r; c < 192; ++c) pairs[off + c - r] = (u16)((r << 8) | c);
  } else if (r == 192) {
    for (int j = 0; j < 64; ++j) pairs[18528 + j] = (u16)((j << 8) | 192);
  } else if (r == 193) {
    for (int j = 18592; j < 18624; ++j) pairs[j] = (u16)((192 << 8) | 192);  // pad (B=0)
  }
}

// pack A (f32 row-major -> bf16 tiles [mt][kt][64][32])
__device__ __forceinline__ void packA_dev(const float* __restrict__ A,
                                          bf16* __restrict__ Ap, int K,
                                          int bx, int by) {
  const int t = threadIdx.x;
  const int KT = K >> 5;
  const size_t tile = ((size_t)bx * KT + by) * (64 * 32);
  const int c = t;
  const int mm = c >> 2, koct = (c & 3) * 8;
  const float* src = A + (size_t)(bx * 64 + mm) * K + by * 32 + koct;
  f32x4 f0 = *(const f32x4*)src;
  f32x4 f1 = *(const f32x4*)(src + 4);
  __align__(16) bf16 h[8];
  h[0]=(bf16)f0[0]; h[1]=(bf16)f0[1]; h[2]=(bf16)f0[2]; h[3]=(bf16)f0[3];
  h[4]=(bf16)f1[0]; h[5]=(bf16)f1[1]; h[6]=(bf16)f1[2]; h[7]=(bf16)f1[3];
  *(i32x4*)(Ap + tile + (size_t)c * 8) = *(const i32x4*)h;
}

// pack B (f32 [K][N] -> bf16 tiles [nt][kt][64][32])
__device__ __forceinline__ void packB_dev(const float* __restrict__ B,
                                          bf16* __restrict__ Bp, int K, int N,
                                          int bx, int by,
                                          float* __restrict__ sLB) {
  const int BNp = 64, LS = 66;
  const int t = threadIdx.x;
  const int KT = K >> 5;
  for (int idx = t; idx < 32 * BNp; idx += 256) {
    const int kk = idx >> 6, nn = idx & 63;
    sLB[kk * LS + nn] = B[(size_t)(by * 32 + kk) * N + bx * BNp + nn];
  }
  __syncthreads();
  const size_t tile = ((size_t)bx * KT + by) * ((size_t)BNp * 32);
  for (int c = t; c < BNp * 4; c += 256) {
    const int nn = c >> 2, koct = (c & 3) * 8;
    __align__(16) bf16 h[8];
#pragma unroll
    for (int j = 0; j < 8; ++j) h[j] = (bf16)sLB[(koct + j) * LS + nn];
    *(i32x4*)(Bp + tile + (size_t)c * 8) = *(const i32x4*)h;
  }
}

// pack tw1 -> fp8 e4m3 tiles [nt 8][kw 291][n 128][k 64 B], values *32.
__device__ __forceinline__ void packTw1_dev(const float* __restrict__ tw1,
                                            u8* __restrict__ Bp, int nt, int kw) {
  const int t = threadIdx.x;
  const int n4 = t & 31, k8 = t >> 5;
  const int kbase = kw * 64 + k8 * 8;
  const int nbase = nt * 128 + n4 * 4;
  f32x4 v[8];
#pragma unroll
  for (int j = 0; j < 8; ++j) {
    const int gk = kbase + j;
    if (gk < 18592) {
      v[j] = *(const f32x4*)(tw1 + (size_t)gk * 1024 + nbase);
      v[j] *= 32.f;
    } else {
      v[j] = f32x4{0.f, 0.f, 0.f, 0.f};
    }
  }
  u8* tile = Bp + ((size_t)nt * 291 + kw) * 8192;
#pragma unroll
  for (int c = 0; c < 4; ++c) {
    int r0 = __builtin_amdgcn_cvt_pk_fp8_f32(v[0][c], v[1][c], 0, false);
    r0 = __builtin_amdgcn_cvt_pk_fp8_f32(v[2][c], v[3][c], r0, true);
    int r1 = __builtin_amdgcn_cvt_pk_fp8_f32(v[4][c], v[5][c], 0, false);
    r1 = __builtin_amdgcn_cvt_pk_fp8_f32(v[6][c], v[7][c], r1, true);
    i32x2 d; d[0] = r0; d[1] = r1;
    *(i32x2*)(tile + (n4 * 4 + c) * 64 + k8 * 8) = d;
  }
}

// ---------------------------------------------------------------- fused prologue
__global__ __launch_bounds__(256) void prologue_kernel(
    const float* __restrict__ xep, const float* __restrict__ xd,
    const float* __restrict__ pw1, const float* __restrict__ pw2,
    const float* __restrict__ bw1, const float* __restrict__ bw2,
    const float* __restrict__ tw1, const float* __restrict__ tw2,
    bf16* Xp, bf16* Xd, bf16* Bpw1, bf16* Bpw2, bf16* Bbw1, bf16* Bbw2,
    u8* Btw1, bf16* Btw2, u16* pairs, float* stats) {
  __shared__ float sLB[32 * 66];
  int i = blockIdx.x;
  if (i < 2328) { packTw1_dev(tw1, Btw1, i & 7, i >> 3); return; }
  i -= 2328;
  if (i < 1536) { packA_dev(xep, Xp, 768, i & 63, i >> 6); return; }
  i -= 1536;
  if (i < 512)  { packA_dev(xd, Xd, 256, i & 63, i >> 6); return; }
  i -= 512;
  if (i < 96)   { packB_dev(pw1, Bpw1, 768, 256, i & 3, i >> 2, sLB); return; }
  i -= 96;
  if (i < 8)    { packB_dev(pw2, Bpw2, 256, 64, 0, i, sLB); return; }
  i -= 8;
  if (i < 64)   { packB_dev(bw1, Bbw1, 256, 512, i & 7, i >> 3, sLB); return; }
  i -= 64;
  if (i < 16)   { packB_dev(bw2, Bbw2, 512, 64, 0, i, sLB); return; }
  i -= 16;
  if (i < 256)  { packB_dev(tw2, Btw2, 1024, 512, i & 7, i >> 3, sLB); return; }
  i -= 256;
  if (i == 0) pairs_dev(pairs, stats);
}

// embedding gather-sum -> cf[:,128:192], 8 rows per block
__device__ __forceinline__ void embed8_dev(const int* __restrict__ xs,
                                           const float* __restrict__ emb,
                                           float* __restrict__ cf, int blk) {
  const int wid = threadIdx.x >> 6, lane = threadIdx.x & 63;
#pragma unroll
  for (int s = 0; s < 2; ++s) {
    const int b = blk * 8 + s * 4 + wid;
    const int* row = xs + (size_t)b * 50;
    float acc = 0.f;
#pragma unroll 10
    for (int h = 0; h < 50; ++h) {
      int idx = row[h];
      acc += emb[(size_t)idx * 64 + lane];
    }
    cf[(size_t)b * 193 + 128 + lane] = acc;
  }
}

// ================================================================ bf16 MFMA GEMM body (small GEMMs)
template <int BM, int BN, int MF, int NF>
__device__ __forceinline__ void gemm_body(
    const bf16* __restrict__ Ap, const bf16* __restrict__ Bp,
    const float* __restrict__ bias,
    float* __restrict__ outF, int ldF,
    bf16* __restrict__ outP, int ktN, int bmsh,
    int KT, int M0, int relu_flag, int bx, int by,
    bf16* sA, bf16* sB, float* statsAcc) {
  const int t = threadIdx.x;
  const int wid = t >> 6, lane = t & 63;
  const int wm = (wid >> 1) * (MF * 16);
  const int wn = (wid & 1) * (NF * 16);
  const int r16 = lane & 15, q = lane >> 4;

  f32x4 acc[MF][NF];
#pragma unroll
  for (int i = 0; i < MF; ++i)
#pragma unroll
    for (int j = 0; j < NF; ++j) acc[i][j] = f32x4{0.f, 0.f, 0.f, 0.f};

  const bf16* aBase = Ap + (size_t)bx * KT * (BM * 32);
  const bf16* bBase = Bp + (size_t)by * KT * (BN * 32);
  constexpr int A_CH = BM * 4;
  constexpr int B_CH = BN * 4;

  for (int kt = 0; kt < KT; ++kt) {
    const bf16* ag = aBase + (size_t)kt * (BM * 32);
    const bf16* bg = bBase + (size_t)kt * (BN * 32);
#pragma unroll
    for (int c = t; c < A_CH; c += 256) {
      const int row = c >> 2, qs = c & 3, qg = (qs - (row >> 1)) & 3;
      async16(sA + c * 8, ag + row * 32 + qg * 8);
    }
#pragma unroll
    for (int c = t; c < B_CH; c += 256) {
      const int row = c >> 2, qs = c & 3, qg = (qs - (row >> 1)) & 3;
      async16(sB + c * 8, bg + row * 32 + qg * 8);
    }
    __syncthreads();
    v8bf af[MF], bfr[NF];
#pragma unroll
    for (int i = 0; i < MF; ++i) {
      const int row = wm + i * 16 + r16;
      af[i] = *(const v8bf*)(sA + row * 32 + (((q + (row >> 1)) & 3) * 8));
    }
#pragma unroll
    for (int j = 0; j < NF; ++j) {
      const int row = wn + j * 16 + r16;
      bfr[j] = *(const v8bf*)(sB + row * 32 + (((q + (row >> 1)) & 3) * 8));
    }
#pragma unroll
    for (int i = 0; i < MF; ++i)
#pragma unroll
      for (int j = 0; j < NF; ++j)
        acc[i][j] = __builtin_amdgcn_mfma_f32_16x16x32_bf16(af[i], bfr[j], acc[i][j], 0, 0, 0);
    __syncthreads();
  }

  float cs[NF], cs2[NF];
#pragma unroll
  for (int j = 0; j < NF; ++j) { cs[j] = 0.f; cs2[j] = 0.f; }

#pragma unroll
  for (int j = 0; j < NF; ++j) {
    const int gn = by * BN + wn + j * 16 + r16;
    const float bv = bias[gn];
#pragma unroll
    for (int i = 0; i < MF; ++i) {
      const int gm0 = M0 + bx * BM + wm + i * 16 + q * 4;
#pragma unroll
      for (int r = 0; r < 4; ++r) {
        float v = acc[i][j][r] + bv;
        if (relu_flag) v = fmaxf(v, 0.f);
        if (statsAcc) { cs[j] += v; cs2[j] += v * v; }
        const int gm = gm0 + r;
        if (outF) outF[(size_t)gm * ldF + gn] = v;
        if (outP) {
          const int mt = gm >> bmsh, mm = gm & ((1 << bmsh) - 1);
          outP[(((size_t)mt * ktN + (gn >> 5)) << (bmsh + 5)) + ((size_t)mm << 5) + (gn & 31)] = (bf16)v;
        }
      }
    }
  }

  if (statsAcc) {
#pragma unroll
    for (int j = 0; j < NF; ++j) {
      float a = cs[j], b2 = cs2[j];
      a += __shfl_xor(a, 16, 64);  a += __shfl_xor(a, 32, 64);
      b2 += __shfl_xor(b2, 16, 64); b2 += __shfl_xor(b2, 32, 64);
      if (q == 0) {
        const int gn = by * BN + wn + j * 16 + r16;
        atomicAdd(&statsAcc[gn], a);
        atomicAdd(&statsAcc[64 + gn], b2);
      }
    }
  }
}

template <int BM, int BN, int MF, int NF>
__global__ __launch_bounds__(256, 2) void gemm_kernel(
    const bf16* __restrict__ Ap, const bf16* __restrict__ Bp,
    const float* __restrict__ bias,
    float* __restrict__ outF, int ldF,
    bf16* __restrict__ outP, int ktN, int bmsh,
    int KT, int M0, int relu_flag) {
  __shared__ __align__(16) bf16 sA[BM * 32];
  __shared__ __align__(16) bf16 sB[BN * 32];
  gemm_body<BM, BN, MF, NF>(Ap, Bp, bias, outF, ldF, outP, ktN, bmsh,
                            KT, M0, relu_flag, blockIdx.x, blockIdx.y, sA, sB, nullptr);
}

// two independent GEMMs (z=0,1) + optional embed slice (z=2)
template <int BM, int BN, int MF, int NF>
__global__ __launch_bounds__(256, 2) void gemm_dual_kernel(
    const bf16* Ap0, const bf16* Bp0, const float* bias0,
    float* outF0, int ldF0, bf16* outP0, int ktN0, int bmsh0, int KT0, int relu0, int gy0,
    float* statsAcc0,
    const bf16* Ap1, const bf16* Bp1, const float* bias1,
    float* outF1, int ldF1, bf16* outP1, int ktN1, int bmsh1, int KT1, int relu1, int gy1,
    const int* xs, const float* emb, float* cf) {
  __shared__ __align__(16) bf16 sA[BM * 32];
  __shared__ __align__(16) bf16 sB[BN * 32];
  if (blockIdx.z == 0) {
    if ((int)blockIdx.y >= gy0) return;
    gemm_body<BM, BN, MF, NF>(Ap0, Bp0, bias0, outF0, ldF0, outP0, ktN0, bmsh0,
                              KT0, 0, relu0, blockIdx.x, blockIdx.y, sA, sB, statsAcc0);
  } else if (blockIdx.z == 1) {
    if ((int)blockIdx.y >= gy1) return;
    gemm_body<BM, BN, MF, NF>(Ap1, Bp1, bias1, outF1, ldF1, outP1, ktN1, bmsh1,
                              KT1, 0, relu1, blockIdx.x, blockIdx.y, sA, sB, nullptr);
  } else {
    embed8_dev(xs, emb, cf, blockIdx.y * 64 + blockIdx.x);
  }
}

// ---------------------------------------------------------------- MX fp8 split-K GEMM -> bf16 partials [S][Mchunk][1024]
// Block tile 256x128 (two A mt-tiles), 4 waves of 128x64 each.
// Per window: A 16KB (4 DMA/thread) + B 8KB (2 DMA/thread) = 24KB/slot,
// 2 slots = 48KB LDS. Per thread per window: 12 ds_read_b128 feed 8 MFMAs.
// Counted-vmcnt window pipeline (pure DMA — see session rule): stage w+1,
// vmcnt(6) retires window w's 6 DMAs, barrier, setprio(1)+MFMA+setprio(0),
// lgkmcnt(0), barrier.
template <int S>
__global__ __launch_bounds__(256, 2) void gemm_splitk_mx(
    const u8* __restrict__ Ap, const u8* __restrict__ Bp,
    bf16* __restrict__ part, int Mchunk) {
  __shared__ __align__(16) u8 sAB[49152];   // 2 slots x (A 16KB + B 8KB)
  const int t = threadIdx.x;
  const int bx = blockIdx.x, by = blockIdx.y, bz = blockIdx.z;
  const int lane = t & 63, wid = t >> 6;
  const int wm2 = (wid >> 1) * 128, wn = (wid & 1) * 64;   // wave tile 128x64
  const int l31 = lane & 31, khalf = lane >> 5;
  const int kw0 = (291 * bz) / S, kw1 = (291 * (bz + 1)) / S;
  const int nw = kw1 - kw0;

  // ---- staging offsets (pre-swizzled source; LDS dst lane-linear) ----
  // chunk c: LDS row = c>>2 (A: 0..255, B: 0..127), slot-quarter qs = c&3,
  // source quarter qg = (qs - (row>>1)) & 3. A rows >=128 live in mt+1.
  const size_t TILE1 = (size_t)291 * 8192;
  size_t aSrc[4]; int aDst[4];
#pragma unroll
  for (int k = 0; k < 4; ++k) {
    const int c = t + 256 * k;
    const int ra = c >> 2;
    const int qg = ((c & 3) - (ra >> 1)) & 3;
    aSrc[k] = (ra >= 128 ? TILE1 + (size_t)(ra - 128) * 64 : (size_t)ra * 64) + qg * 16;
    aDst[k] = t * 16 + k * 4096;
  }
  size_t bSrc[2]; int bDst[2];
#pragma unroll
  for (int k = 0; k < 2; ++k) {
    const int c = t + 256 * k;
    const int rb = c >> 2;
    const int qg = ((c & 3) - (rb >> 1)) & 3;
    bSrc[k] = (size_t)rb * 64 + qg * 16;
    bDst[k] = 16384 + t * 16 + k * 4096;
  }

  // ---- read fragment LDS offsets (swizzled quarters) ----
  int fa0[4], fa1[4], fb0[2], fb1[2];
#pragma unroll
  for (int i = 0; i < 4; ++i) {
    const int ra = wm2 + i * 32 + l31;
    const int qa = (khalf * 2 + (ra >> 1)) & 3;
    fa0[i] = ra * 64 + qa * 16;
    fa1[i] = ra * 64 + (((qa + 1) & 3) << 4);
  }
#pragma unroll
  for (int j = 0; j < 2; ++j) {
    const int rb = wn + j * 32 + l31;
    const int qb = (khalf * 2 + (rb >> 1)) & 3;
    fb0[j] = 16384 + rb * 64 + qb * 16;
    fb1[j] = 16384 + rb * 64 + (((qb + 1) & 3) << 4);
  }

  f32x16 acc[4][2];
#pragma unroll
  for (int i = 0; i < 4; ++i)
#pragma unroll
    for (int j = 0; j < 2; ++j)
#pragma unroll
      for (int r = 0; r < 16; ++r) acc[i][j][r] = 0.f;

  const u8* agp = Ap + ((size_t)(bx * 2) * 291 + kw0) * 8192;
  const u8* bgp = Bp + ((size_t)by * 291 + kw0) * 8192;

  auto stageW = [&](int w) {                 // exactly 6 DMAs per call
    const int slot = (w & 1) * 24576;
    const u8* ag = agp + (size_t)w * 8192;
    const u8* bg = bgp + (size_t)w * 8192;
#pragma unroll
    for (int k = 0; k < 4; ++k) async16(&sAB[slot + aDst[k]], ag + aSrc[k]);
#pragma unroll
    for (int k = 0; k < 2; ++k) async16(&sAB[slot + bDst[k]], bg + bSrc[k]);
  };

  auto compute = [&](int off) {
    v8i32 bv[2];
#pragma unroll
    for (int j = 0; j < 2; ++j) {
      union { i32x4 h[2]; v8i32 v; } ub;
      ub.h[0] = *(const i32x4*)&sAB[fb0[j] + off];
      ub.h[1] = *(const i32x4*)&sAB[fb1[j] + off];
      bv[j] = ub.v;
    }
#pragma unroll
    for (int i = 0; i < 4; ++i) {
      union { i32x4 h[2]; v8i32 v; } ua;
      ua.h[0] = *(const i32x4*)&sAB[fa0[i] + off];
      ua.h[1] = *(const i32x4*)&sAB[fa1[i] + off];
      acc[i][0] = __builtin_amdgcn_mfma_scale_f32_32x32x64_f8f6f4(
          ua.v, bv[0], acc[i][0], 0, 0, 0, 0x7F7F7F7F, 0, 0x7A7A7A7A);
      acc[i][1] = __builtin_amdgcn_mfma_scale_f32_32x32x64_f8f6f4(
          ua.v, bv[1], acc[i][1], 0, 0, 0, 0x7F7F7F7F, 0, 0x7A7A7A7A);
    }
  };

  stageW(0);                                  // 6 outstanding
  for (int w = 0; w < nw; ++w) {
    if (w + 1 < nw) {
      stageW(w + 1);                          // +6 -> 12 outstanding
      asm volatile("s_waitcnt vmcnt(6)" ::: "memory");   // retire window w's 6
    } else {
      asm volatile("s_waitcnt vmcnt(0)" ::: "memory");   // final window: drain
    }
    __builtin_amdgcn_s_barrier();             // window w resident for all waves
    __builtin_amdgcn_sched_barrier(0);        // no ds_read hoists above barrier
    __builtin_amdgcn_s_setprio(1);            // T5: favor MFMA-issuing wave
    compute((w & 1) * 24576);
    __builtin_amdgcn_s_setprio(0);
    if (w + 1 < nw) {
      asm volatile("s_waitcnt lgkmcnt(0)" ::: "memory"); // ds_reads drained
      __builtin_amdgcn_s_barrier();           // slot free for stageW(w+2)
    }
  }

  bf16* pBase = part + (size_t)bz * Mchunk * 1024;
#pragma unroll
  for (int i = 0; i < 4; ++i)
#pragma unroll
    for (int j = 0; j < 2; ++j) {
      const int gn = by * 128 + wn + j * 32 + l31;
#pragma unroll
      for (int r = 0; r < 16; ++r) {
        const int gm = bx * 256 + wm2 + i * 32 + (r & 3) + 8 * (r >> 2) + 4 * khalf;
        pBase[(size_t)gm * 1024 + gn] = (bf16)acc[i][j][r];
      }
    }
}

// ---------------------------------------------------------------- split-K reduce -> t1 packed bf16 (BM=64)
__global__ __launch_bounds__(256) void reducek_kernel(const bf16* __restrict__ part,
                                                      const float* __restrict__ bias,
                                                      bf16* __restrict__ t1,
                                                      int S, int Mchunk, int M0) {
  const int idx = blockIdx.x * 256 + threadIdx.x;
  const int gm = idx >> 7;
  const int gn8 = (idx & 127) * 8;
  float v[8] = {0.f, 0.f, 0.f, 0.f, 0.f, 0.f, 0.f, 0.f};
  for (int s = 0; s < S; ++s) {
    v8bf p = *(const v8bf*)(part + ((size_t)s * Mchunk + gm) * 1024 + gn8);
#pragma unroll
    for (int r = 0; r < 8; ++r) v[r] += (float)p[r];
  }
  const f32x4 b0 = *(const f32x4*)(bias + gn8);
  const f32x4 b1 = *(const f32x4*)(bias + gn8 + 4);
  __align__(16) bf16 h[8];
#pragma unroll
  for (int r = 0; r < 4; ++r) h[r] = (bf16)fmaxf(v[r] + b0[r], 0.f);
#pragma unroll
  for (int r = 0; r < 4; ++r) h[4 + r] = (bf16)fmaxf(v[4 + r] + b1[r], 0.f);
  const int G = M0 + gm;
  const int mt = G >> 6, mm = G & 63, kt = gn8 >> 5;
  *(i32x4*)(t1 + (((size_t)mt * 32 + kt) << 11) + (mm << 5) + (gn8 & 31)) = *(const i32x4*)h;
}

// ---------------------------------------------------------------- interaction A -> fp8 tiles [mt][kw 291][128][64]
__global__ __launch_bounds__(256, 2) void agen_kernel(const float* __restrict__ cf,
                                                      const float* __restrict__ z,
                                                      const float* __restrict__ gsum,
                                                      const float* __restrict__ gamma,
                                                      const float* __restrict__ beta,
                                                      const u16* __restrict__ pairs,
                                                      u8* __restrict__ Ap,
                                                      float* __restrict__ dout,
                                                      int rowBase) {
  __shared__ float sCF[64 * 193];
  __shared__ float sMu[64], sRstd[64];
  const int t = threadIdx.x;
  const int gRow0 = rowBase + blockIdx.x * 64;
  // bottom cols 0:64
  for (int idx = t; idx < 64 * 64; idx += 256) {
    const int r = idx >> 6, c = idx & 63;
    sCF[r * 193 + c] = cf[(size_t)(gRow0 + r) * 193 + c];
  }
  // embed cols 128:192
  for (int idx = t; idx < 64 * 64; idx += 256) {
    const int r = idx >> 6, c = idx & 63;
    sCF[r * 193 + 128 + c] = cf[(size_t)(gRow0 + r) * 193 + 128 + c];
  }
  if (t < 64) {
    const float mu = gsum[t] * (1.f / 4096.f);
    const float var = gsum[64 + t] * (1.f / 4096.f) - mu * mu;
    sMu[t] = mu;
    sRstd[t] = rsqrtf(var + 1e-5f);
    sCF[t * 193 + 192] = 1.f;
  }
  __syncthreads();
  // normalize z -> cols 64:128 (+ dout tail once)
  for (int idx = t; idx < 64 * 64; idx += 256) {
    const int r = idx >> 6, c = idx & 63;
    const float xe = gamma[c] * (z[(size_t)(gRow0 + r) * 64 + c] - sMu[c]) * sRstd[c] + beta[c];
    sCF[r * 193 + 64 + c] = xe;
    if (blockIdx.y == 0) dout[4096 + (size_t)(gRow0 + r) * 64 + c] = xe;
  }
  __syncthreads();

  const int kw0 = (291 * blockIdx.y) / 8;
  const int kw1 = (291 * (blockIdx.y + 1)) / 8;
  const int row = t >> 2, kq = t & 3;
  const int mt = blockIdx.x >> 1;
  const int mrow = (blockIdx.x & 1) * 64 + row;
  const float* myrow = sCF + row * 193;
  for (int kw = kw0; kw < kw1; ++kw) {
    const int kb = kw * 64 + kq * 16;
    i32x4 d;
    if (kb >= 18592) {
      d = i32x4{0, 0, 0, 0};
    } else {
      union { i32x4 v4[2]; u16 u[16]; } P;
      P.v4[0] = *(const i32x4*)(pairs + kb);
      P.v4[1] = *(const i32x4*)(pairs + kb + 8);
#pragma unroll
      for (int g = 0; g < 4; ++g) {
        float p[4];
#pragma unroll
        for (int j = 0; j < 4; ++j) {
          const u16 pr = P.u[g * 4 + j];
          p[j] = myrow[pr >> 8] * myrow[pr & 255];
        }
        int r = __builtin_amdgcn_cvt_pk_fp8_f32(p[0], p[1], 0, false);
        r = __builtin_amdgcn_cvt_pk_fp8_f32(p[2], p[3], r, true);
        d[g] = r;
      }
    }
    *(i32x4*)(Ap + (((size_t)mt * 291 + kw) * 128 + mrow) * 64 + kq * 16) = d;
  }
}

// ---------------------------------------------------------------- final dot (512->1) + sigmoid; t2 packed bf16 (BM=64, N=512)
__global__ __launch_bounds__(256) void topdot_kernel(const bf16* __restrict__ t2p,
                                                     const float* __restrict__ w,
                                                     const float* __restrict__ b3,
                                                     float* __restrict__ dout) {
  const int wid = threadIdx.x >> 6, lane = threadIdx.x & 63;
  const int b = blockIdx.x * 4 + wid;
  // lane covers n = lane*8 .. lane*8+7
  const size_t addr = ((((size_t)(b >> 6) * 16) + (lane >> 2)) << 11) +
                      ((size_t)(b & 63) << 5) + (lane & 3) * 8;
  v8bf p = *(const v8bf*)(t2p + addr);
  const float* wv = w + lane * 8;
  float s = 0.f;
#pragma unroll
  for (int r = 0; r < 8; ++r) s += (float)p[r] * wv[r];
  for (int m = 32; m > 0; m >>= 1) s += __shfl_xor(s, m, 64);
  if (lane == 0) dout[b] = 1.f / (1.f + __expf(-(s + b3[0])));
}

// ================================================================ launch
extern "C" void kernel_launch(void* const* d_in, const int* in_sizes, int n_in,
                              void* d_out, int out_size, void* d_ws, size_t ws_size,
                              hipStream_t stream) {
  const int*   xs   = (const int*)  d_in[0];
  const float* xd   = (const float*)d_in[1];
  const float* xep  = (const float*)d_in[2];
  const float* emb  = (const float*)d_in[3];
  const float* pw1  = (const float*)d_in[4];
  const float* pb1  = (const float*)d_in[5];
  const float* pw2  = (const float*)d_in[6];
  const float* pb2  = (const float*)d_in[7];
  const float* gmma = (const float*)d_in[8];
  const float* beta = (const float*)d_in[9];
  const float* bw1  = (const float*)d_in[10];
  const float* bb1  = (const float*)d_in[11];
  const float* bw2  = (const float*)d_in[12];
  const float* bb2  = (const float*)d_in[13];
  const float* tw1  = (const float*)d_in[14];
  const float* tb1  = (const float*)d_in[15];
  const float* tw2  = (const float*)d_in[16];
  const float* tb2  = (const float*)d_in[17];
  const float* tw3  = (const float*)d_in[18];
  const float* tb3  = (const float*)d_in[19];
  float* out = (float*)d_out;

  uint8_t* base = (uint8_t*)d_ws;
  size_t off = 0;
  auto alloc = [&](size_t b) {
    void* p = base + off;
    off = (off + b + 511) & ~((size_t)511);
    return p;
  };
  u16*  pairs = (u16*) alloc((size_t)18624 * 2);
  bf16* Xp    = (bf16*)alloc((size_t)4096 * 768 * 2);
  bf16* Xd    = (bf16*)alloc((size_t)4096 * 256 * 2);
  bf16* Bpw1  = (bf16*)alloc((size_t)768 * 256 * 2);
  bf16* Bpw2  = (bf16*)alloc((size_t)256 * 64 * 2);
  bf16* Bbw1  = (bf16*)alloc((size_t)256 * 512 * 2);
  bf16* Bbw2  = (bf16*)alloc((size_t)512 * 64 * 2);
  u8*   Btw1  = (u8*)  alloc((size_t)8 * 291 * 8192);
  bf16* Btw2  = (bf16*)alloc((size_t)1024 * 512 * 2);
  bf16* hbuf  = (bf16*)alloc((size_t)4096 * 256 * 2);
  float* z    = (float*)alloc((size_t)4096 * 64 * 4);
  float* stats= (float*)alloc((size_t)128 * 4);
  bf16* b0    = (bf16*)alloc((size_t)4096 * 512 * 2);
  float* cf   = (float*)alloc((size_t)4096 * 193 * 4);
  bf16* t1    = (bf16*)alloc((size_t)4096 * 1024 * 2);
  bf16* t2p   = (bf16*)alloc((size_t)4096 * 512 * 2);
  size_t fixedEnd = off;

  // pick (chunk, S): Ap fp8 = chunk*18624 B; partK bf16 = S*chunk*1024*2 B
  int chunk = 512, S = 8;
  {
    const int candC[5] = {4096, 2048, 2048, 1024, 512};
    const int candS[5] = {4, 8, 4, 8, 8};
    for (int i = 0; i < 5; ++i) {
      size_t need = fixedEnd + (size_t)candC[i] * 18624 + 1024 +
                    (size_t)candS[i] * candC[i] * 1024 * 2 + 1024;
      if (need <= ws_size) { chunk = candC[i]; S = candS[i]; break; }
    }
  }
  u8*   ApBig = (u8*)  alloc((size_t)chunk * 18624);
  bf16* partK = (bf16*)alloc((size_t)S * chunk * 1024 * 2);

  // ---- fused prologue (packs + pairs + stats zero) ----
  prologue_kernel<<<4817, 256, 0, stream>>>(
      xep, xd, pw1, pw2, bw1, bw2, tw1, tw2,
      Xp, Xd, Bpw1, Bpw2, Bbw1, Bbw2, Btw1, Btw2, pairs, stats);

  // ---- dual1: proj1 || bot1 || embed (z=2) ----
  gemm_dual_kernel<64, 64, 2, 2><<<dim3(64, 8, 3), 256, 0, stream>>>(
      Xp, Bpw1, pb1, nullptr, 0, hbuf, 8, 6, 24, 1, 4, nullptr,
      Xd, Bbw1, bb1, nullptr, 0, b0, 16, 6, 8, 1, 8,
      xs, emb, cf);
  // ---- dual2: proj2 (h@pw2 -> z f32 + BN stats atomics) || bot2 -> cf[:,0:64] ----
  gemm_dual_kernel<64, 64, 2, 2><<<dim3(64, 1, 2), 256, 0, stream>>>(
      hbuf, Bpw2, pb2, z, 64, nullptr, 0, 0, 8, 0, 1, stats,
      b0, Bbw2, bb2, cf, 193, nullptr, 0, 0, 16, 1, 1,
      nullptr, nullptr, nullptr);

  // ---- interaction (fp8, BN fused) + MX split-K GEMM + reduce ----
  for (int c0 = 0; c0 < 4096; c0 += chunk) {
    agen_kernel<<<dim3(chunk / 64, 8), 256, 0, stream>>>(
        cf, z, stats, gmma, beta, pairs, ApBig, out, c0);
    if (S == 4)
      gemm_splitk_mx<4><<<dim3(chunk / 256, 8, 4), 256, 0, stream>>>(
          ApBig, Btw1, partK, chunk);
    else
      gemm_splitk_mx<8><<<dim3(chunk / 256, 8, 8), 256, 0, stream>>>(
          ApBig, Btw1, partK, chunk);
    reducek_kernel<<<chunk / 2, 256, 0, stream>>>(partK, tb1, t1, S, chunk, c0);
  }

  // ---- top2: t2p = relu(t1@tw2+tb2) packed bf16 ----
  gemm_kernel<64, 64, 2, 2><<<dim3(64, 8), 256, 0, stream>>>(
      t1, Btw2, tb2, nullptr, 0, t2p, 16, 6, 32, 0, 1);
  // ---- top3: sigmoid(t2p@tw3+tb3) -> out[0:4096] ----
  topdot_kernel<<<1024, 256, 0, stream>>>(t2p, tw3, tb3, out);
}